// Round 10
// baseline (187.317 us; speedup 1.0000x reference)
//
#include <hip/hip_runtime.h>

// Problem constants
#define B_    1024
#define C_    128
#define ELL   16
#define EQ    3
#define E_    10
#define P3    23
#define P2    5
#define NROW  48              // EQ*ELL rows per (e,c)
#define NIDX  152             // 136 packed upper-tri (v<=i) quad coeffs + 16 linear
#define KD    28              // folded weight depth: 23 (wmax) + 5 (w2)
#define SRS   (NROW * NIDX)   // 7296 floats per (e,c) S-slice

// ws layout (bytes)
#define WS_CNT   0
#define WS_LIST  64
#define WS_S     65536
#define WS_NEED  ((size_t)WS_S + (size_t)E_ * C_ * SRS * 4)   // ~37.4 MB

// ---------------------------------------------------------------------------
// Bucketing: bucket batch indices by element, pad each bucket to x128 by
// replicating the last real index (k_main then needs no load guards).
__device__ void do_lists(const float* __restrict__ y, int* __restrict__ cnt_g,
                         int* __restrict__ list_g, int t) {
    __shared__ int lcnt[E_];
    if (t < E_) lcnt[t] = 0;
    __syncthreads();
    for (int r = 0; r < 4; ++r) {
        int b = t + 256 * r;
        int e = 0;
        #pragma unroll
        for (int j = 1; j < E_; ++j)
            if (y[b * E_ + j] > 0.5f) e = j;
        int slot = atomicAdd(&lcnt[e], 1);
        list_g[e * B_ + slot] = b;
    }
    __syncthreads();
    if (t < E_) {
        int c0 = lcnt[t];
        cnt_g[t] = c0;
        int last = (c0 > 0) ? list_g[t * B_ + c0 - 1] : 0;
        int cp = (c0 + 127) & ~127;
        if (cp > B_) cp = B_;
        for (int s2 = c0; s2 < cp; ++s2) list_g[t * B_ + s2] = last;
    }
}

// ---------------------------------------------------------------------------
// k_s: build S[e][c][rw], rw = j*NIDX + idx.
//  idx<136: packed (v<=i): S = sum_k (U3[j,v,i,k] + (v!=i)U3[j,i,v,k]) * wmax[e,k,c]
//  idx in [136,152): v=idx-136: S = sum_q U2[j,v,q] * w2[e,q,c]   (nu=2 linear term)
// One thread owns roword pair (2t, 2t+1): symmetric coeffs in registers,
// loops 32 c with the folded weight table WL (wmax||w2) broadcast from LDS,
// coalesced float2 stores (mirrors the round-4..8 k_v3g structure that worked).
// grid (16, E, 4): bx<15 are 512-roword tiles; block (15,0,0) does bucketing.
__global__ __launch_bounds__(256, 2) void k_s(const float* __restrict__ U3,
                                              const float* __restrict__ U2,
                                              const float* __restrict__ wmax,
                                              const float* __restrict__ w2,
                                              const float* __restrict__ y,
                                              float* __restrict__ Sg,
                                              int* __restrict__ cnt_g,
                                              int* __restrict__ list_g) {
    const int t = threadIdx.x;
    if (blockIdx.x == 15) {
        if (blockIdx.y == 0 && blockIdx.z == 0) do_lists(y, cnt_g, list_g, t);
        return;
    }
    __shared__ __align__(16) float WL[KD * 32];
    const int e  = blockIdx.y;
    const int cq = blockIdx.z;

    for (int idx = t; idx < KD * 32; idx += 256) {
        int k = idx >> 5, cc = idx & 31, c = cq * 32 + cc;
        WL[idx] = (k < 23) ? wmax[(e * P3 + k) * C_ + c]
                           : w2[(e * P2 + (k - 23)) * C_ + c];
    }
    __syncthreads();

    const int rw0 = blockIdx.x * 512 + 2 * t;
    if (rw0 >= SRS) return;          // partial last tile (SRS even, pair-safe)

    float sk[2][KD];
    #pragma unroll
    for (int h = 0; h < 2; ++h)
        #pragma unroll
        for (int k = 0; k < KD; ++k) sk[h][k] = 0.f;

    for (int h = 0; h < 2; ++h) {
        int rw = rw0 + h;
        int j  = rw / NIDX;
        int idx = rw - j * NIDX;
        if (idx < 136) {
            // unrank packed upper-tri index -> (v, i), v<=i (v-outer ordering)
            int v = 0, rem = idx;
            while (rem >= ELL - v) { rem -= ELL - v; ++v; }
            int i = v + rem;
            const float* ub = U3 + (size_t)j * (ELL * ELL * P3);
            const float* pa = ub + (v * ELL + i) * P3;
            const float* pb = ub + (i * ELL + v) * P3;
            if (v != i) {
                for (int k = 0; k < P3; ++k) sk[h][k] = pa[k] + pb[k];
            } else {
                for (int k = 0; k < P3; ++k) sk[h][k] = pa[k];
            }
        } else {
            int v = idx - 136;
            #pragma unroll
            for (int q = 0; q < P2; ++q)
                sk[h][23 + q] = U2[(size_t)j * (ELL * P2) + v * P2 + q];
        }
    }

    float* vb = Sg + (size_t)(e * C_ + cq * 32) * SRS + rw0;
    #pragma unroll
    for (int g = 0; g < 8; ++g) {
        float a0[4], a1[4];
        #pragma unroll
        for (int q = 0; q < 4; ++q) { a0[q] = 0.f; a1[q] = 0.f; }
        #pragma unroll
        for (int k = 0; k < KD; ++k) {
            float4 wk = *(const float4*)&WL[k * 32 + 4 * g];
            a0[0] += sk[0][k] * wk.x; a1[0] += sk[1][k] * wk.x;
            a0[1] += sk[0][k] * wk.y; a1[1] += sk[1][k] * wk.y;
            a0[2] += sk[0][k] * wk.z; a1[2] += sk[1][k] * wk.z;
            a0[3] += sk[0][k] * wk.w; a1[3] += sk[1][k] * wk.w;
        }
        #pragma unroll
        for (int q = 0; q < 4; ++q) {
            float2 o; o.x = a0[q]; o.y = a1[q];
            *(float2*)(vb + (size_t)(g * 4 + q) * SRS) = o;
        }
    }
}

// ---------------------------------------------------------------------------
// k_main: one THREAD = one (b,c). grid (C_, E_), 128 threads (2 waves).
// p[152] = {x_v*x_i (v<=i packed), x_0..x_15} in VGPRs, built once, reused
// across all 48 rows. S-row addresses are block-uniform -> scalar/broadcast
// loads (SGPR operands) -> near-zero LDS/VMEM pressure in the hot loop.
// Per row: 38 uniform float4 loads + 152 FMA + 1 ds_read_b32 (dynamic x_own;
// LDS avoids dynamic VGPR indexing which would force scratch) + nu1 fold.
// Row loop kept dynamic (unroll disable) for I$ and uniform s_load batching.
__global__ __launch_bounds__(128, 2) void k_main(
    const float* __restrict__ x, const float* __restrict__ Sg,
    const float* __restrict__ U1, const float* __restrict__ w1,
    const int* __restrict__ cnt_g, const int* __restrict__ list_g,
    float* __restrict__ out) {

    __shared__ float XL[128 * 17];   // per-thread x stash, stride 17 (17t+v)%32 conflict-free

    const int t = threadIdx.x;
    const int c = blockIdx.x, e = blockIdx.y;
    const int cnt  = cnt_g[e];
    const int cntp = (cnt + 127) & ~127;
    const float w1s = w1[e * C_ + c];
    const float* sp0 = Sg + (size_t)(e * C_ + c) * SRS;

    #pragma clang loop unroll(disable)
    for (int base = 0; base < cntp; base += 128) {
        const int b = list_g[e * B_ + base + t];
        const float* xb = x + ((size_t)b * C_ + c) * ELL;

        float xr[16];
        #pragma unroll
        for (int i4 = 0; i4 < 4; ++i4) {
            float4 v = ((const float4*)xb)[i4];
            xr[4 * i4 + 0] = v.x; xr[4 * i4 + 1] = v.y;
            xr[4 * i4 + 2] = v.z; xr[4 * i4 + 3] = v.w;
        }
        #pragma unroll
        for (int v = 0; v < 16; ++v) XL[t * 17 + v] = xr[v];  // same-lane use only

        float p[NIDX];
        {
            int n = 0;
            #pragma unroll
            for (int v = 0; v < 16; ++v)
                #pragma unroll
                for (int i = v; i < 16; ++i) p[n++] = xr[v] * xr[i];
            #pragma unroll
            for (int v = 0; v < 16; ++v) p[136 + v] = xr[v];
        }

        float ow0 = 0.f, ow1 = 0.f, ow2 = 0.f;
        #pragma clang loop unroll(disable)
        for (int j = 0; j < NROW; ++j) {
            const float4* sp = (const float4*)(sp0 + j * NIDX);  // uniform
            float a0 = 0.f, a1 = 0.f, a2 = 0.f, a3 = 0.f;
            #pragma unroll
            for (int q = 0; q < 38; ++q) {
                float4 sv = sp[q];
                a0 += sv.x * p[4 * q + 0];
                a1 += sv.y * p[4 * q + 1];
                a2 += sv.z * p[4 * q + 2];
                a3 += sv.w * p[4 * q + 3];
            }
            float t2 = (a0 + a1) + (a2 + a3);
            float xo = XL[t * 17 + (j & 15)];           // dynamic x_own via LDS
            float cb = (t2 + U1[j] * w1s) * xo;         // U1[j] uniform s_load
            if (j < 16) ow0 += cb; else if (j < 32) ow1 += cb; else ow2 += cb;
        }

        if (base + t < cnt) {
            float* op = out + (size_t)b * (C_ * EQ) + c * EQ;
            op[0] = ow0; op[1] = ow1; op[2] = ow2;
        }
    }
}

// ---------------------------------------------------------------------------
extern "C" void kernel_launch(void* const* d_in, const int* in_sizes, int n_in,
                              void* d_out, int out_size, void* d_ws, size_t ws_size,
                              hipStream_t stream) {
    const float* x    = (const float*)d_in[0];
    const float* y    = (const float*)d_in[1];
    const float* U3   = (const float*)d_in[2];
    const float* U2   = (const float*)d_in[3];
    const float* U1   = (const float*)d_in[4];
    const float* wmax = (const float*)d_in[5];
    const float* w2   = (const float*)d_in[6];
    const float* w1   = (const float*)d_in[7];
    float* out = (float*)d_out;
    char*  ws  = (char*)d_ws;

    int*   cnt_g  = (int*)(ws + WS_CNT);
    int*   list_g = (int*)(ws + WS_LIST);
    float* Sg     = (float*)(ws + WS_S);

    // ws_size confirmed >= 66 MB in rounds 1-9; WS_NEED is ~37.4 MB.
    (void)ws_size;

    k_s<<<dim3(16, E_, 4), 256, 0, stream>>>(U3, U2, wmax, w2, y, Sg, cnt_g, list_g);
    k_main<<<dim3(C_, E_), 128, 0, stream>>>(x, Sg, U1, w1, cnt_g, list_g, out);
}